// Round 2
// baseline (1016.883 us; speedup 1.0000x reference)
//
#include <hip/hip_runtime.h>
#include <hip/hip_bf16.h>

#define DEVI __device__ __forceinline__

typedef short bf16x8 __attribute__((ext_vector_type(8)));
typedef float f32x4  __attribute__((ext_vector_type(4)));

static constexpr int Bb   = 128;
static constexpr int Ss   = 512;
static constexpr int Hh   = 1024;
static constexpr int Ee   = 512;
static constexpr int Vv   = 50257;
static constexpr int TWOH = 2048;

DEVI short f2bf(float f){ __hip_bfloat16 h = __float2bfloat16(f); return *reinterpret_cast<short*>(&h); }
DEVI float bf2f(short s){ __hip_bfloat16 h = *reinterpret_cast<__hip_bfloat16*>(&s); return __bfloat162float(h); }

DEVI bf16x8 pack8(f32x4 a, f32x4 b){
  bf16x8 v;
  v[0]=f2bf(a[0]); v[1]=f2bf(a[1]); v[2]=f2bf(a[2]); v[3]=f2bf(a[3]);
  v[4]=f2bf(b[0]); v[5]=f2bf(b[1]); v[6]=f2bf(b[2]); v[7]=f2bf(b[3]);
  return v;
}

DEVI void gld_lds16(const void* g, void* l){
  __builtin_amdgcn_global_load_lds((const __attribute__((address_space(1))) void*)g,
                                   (__attribute__((address_space(3))) void*)l, 16, 0, 0);
}

DEVI f32x4 mfma16(bf16x8 a, bf16x8 b, f32x4 c){
  return __builtin_amdgcn_mfma_f32_16x16x32_bf16(a, b, c, 0, 0, 0);
}

// ---------------- prep: convert W_ae->bf16, h->bf16, gather emb into x_bf16 ----------------
__global__ void k_prep(const float* __restrict__ wae, short* __restrict__ waeb,
                       const float* __restrict__ h, short* __restrict__ hb,
                       const int* __restrict__ dec_in, const float* __restrict__ emb,
                       short* __restrict__ xb)
{
  const int total_wae = Hh*TWOH;
  const int total_h   = Bb*Hh;
  const int total_emb = Bb*Ee;
  const int total = total_wae + total_h + total_emb;
  for (int i = blockIdx.x*blockDim.x + threadIdx.x; i < total; i += gridDim.x*blockDim.x){
    if (i < total_wae) waeb[i] = f2bf(wae[i]);
    else if (i < total_wae + total_h){ int j = i - total_wae; hb[j] = f2bf(h[j]); }
    else {
      int j = i - total_wae - total_h;
      int b = j >> 9, e = j & 511;
      xb[b*2560 + e] = f2bf(emb[(size_t)dec_in[b]*Ee + e]);
    }
  }
}

// ---------------- scores GEMM: M=65536 x N=1024 x K=2048, fused tanh-reduce ------
// XCD grouping: the 8 n-tiles of one row-tile are consecutive within one XCD's
// round-robin stream -> A tile (512KB) stays L2-resident, read from HBM once.
// T2 XOR swizzle (byte ^= (row&7)<<4) on both LDS tiles kills the 16-way conflict.
// nb==0 blocks additionally persist the bf16-converted A tile to encb for k_ctx.
__launch_bounds__(256)
__global__ void k_scores(const float* __restrict__ enc, const short* __restrict__ waeb,
                         const float* __restrict__ ahb, const float* __restrict__ b_ah,
                         const float* __restrict__ b_ae, const float* __restrict__ wsc,
                         float* __restrict__ scores, short* __restrict__ encb)
{
  __shared__ __align__(16) short As[128*64];
  __shared__ __align__(16) short Bs[128*64];
  const int q   = blockIdx.x;
  const int xcd = q & 7;
  const int sgr = q >> 3;
  const int nb  = sgr & 7;
  const int rt  = xcd + ((sgr >> 3) << 3);       // 0..511
  const int tid = threadIdx.x, wid = tid>>6, lane = tid&63;
  const int wr = wid>>1, wc = wid&1;
  const int srow = lane>>3, l7 = lane&7;
  const int c0 = wid*4;
  f32x4 acc[4][4] = {};
  const float* Ab  = enc  + (size_t)rt*128*TWOH;
  const short* Bbp = waeb + (size_t)nb*128*TWOH;
  const bool wr_enc = (nb == 0) && (encb != nullptr);

  for (int kt = 0; kt < 32; ++kt){
    const int k0 = kt*64;
    #pragma unroll
    for (int i=0;i<4;++i){                          // A: fp32 -> bf16 reg-staged, swizzled write
      int c = c0+i, row = c*8 + srow;
      const float* bp = Ab + (size_t)row*TWOH + k0 + l7*8;
      f32x4 f0 = *(const f32x4*)bp, f1 = *(const f32x4*)(bp+4);
      bf16x8 pk = pack8(f0, f1);
      *(bf16x8*)((char*)As + row*128 + ((l7^srow)<<4)) = pk;
      if (wr_enc) *(bf16x8*)(encb + (size_t)(rt*128+row)*TWOH + k0 + l7*8) = pk;
    }
    #pragma unroll
    for (int i=0;i<4;++i){                          // B: bf16 direct-to-LDS, pre-swizzled src
      int c = c0+i, row = c*8 + srow;
      gld_lds16(Bbp + (size_t)row*TWOH + k0 + ((l7^srow)*8), (char*)Bs + c*1024);
    }
    __syncthreads();
    #pragma unroll
    for (int kk=0;kk<2;++kk){
      bf16x8 af[4], bq[4];
      const int ko = kk*64 + (lane>>4)*16;
      const int sw = ko ^ (l7<<4);
      #pragma unroll
      for (int i=0;i<4;++i) af[i] = *(const bf16x8*)((const char*)As + (wr*64+i*16+(lane&15))*128 + sw);
      #pragma unroll
      for (int j=0;j<4;++j) bq[j] = *(const bf16x8*)((const char*)Bs + (wc*64+j*16+(lane&15))*128 + sw);
      #pragma unroll
      for (int i=0;i<4;++i)
        #pragma unroll
        for (int j=0;j<4;++j)
          acc[i][j] = mfma16(af[i], bq[j], acc[i][j]);
    }
    __syncthreads();
  }
  // epilogue: scores[m] += sum_n tanh(ah[b,n]+b_ah+b_ae+ae)*w_score[n]
  const int lo = lane&15, hi = lane>>4;
  const int b = rt>>2;
  float w4[4], t4[4];
  #pragma unroll
  for (int j=0;j<4;++j){
    int n = nb*128 + wc*64 + j*16 + lo;
    w4[j] = wsc[n];
    t4[j] = ahb[b*Hh + n] + b_ah[n] + b_ae[n];
  }
  #pragma unroll
  for (int i=0;i<4;++i){
    #pragma unroll
    for (int q2=0;q2<4;++q2){
      int m = rt*128 + wr*64 + i*16 + hi*4 + q2;
      float s = 0.f;
      #pragma unroll
      for (int j=0;j<4;++j) s += tanhf(t4[j] + acc[i][j][q2]) * w4[j];
      s += __shfl_xor(s,1); s += __shfl_xor(s,2); s += __shfl_xor(s,4); s += __shfl_xor(s,8);
      if (lo == 0) atomicAdd(&scores[m], s);
    }
  }
}

// ---------------- generic 128-row GEMM: A[128,K] bf16 ws, B[N,K] fp32 global --------------
template<int MODE>
__launch_bounds__(256)
__global__ void k_gemm128(const short* __restrict__ A, int lda,
                          const float* __restrict__ B0, const float* __restrict__ B1,
                          float* __restrict__ O0, float* __restrict__ O1,
                          const float* __restrict__ bias, int kiters)
{
  __shared__ __align__(16) short As[128*64];
  __shared__ __align__(16) short Bs[128*64];
  const int nb = blockIdx.x;
  const int tid = threadIdx.x, wid = tid>>6, lane = tid&63;
  const int wr = wid>>1, wc = wid&1;
  const int srow = lane>>3, l7 = lane&7;
  const int c0 = wid*4;

  const float* Bt; int noff; float* Ot; int ostride;
  if constexpr (MODE==0){
    if (nb < 8){ Bt = B0; noff = 0;    Ot = O0; ostride = Hh;   }
    else       { Bt = B1; noff = 1024; Ot = O1; ostride = 3*Hh; }
  } else if constexpr (MODE==1){ Bt = B0; noff = 0; Ot = O0; ostride = 3*Hh; }
  else { Bt = B0; noff = 0; Ot = O0; ostride = Vv; }

  f32x4 acc[4][4] = {};
  const int kt0 = blockIdx.y * kiters;
  for (int kt = kt0; kt < kt0 + kiters; ++kt){
    const int k0 = kt*64;
    #pragma unroll
    for (int i=0;i<4;++i){                          // A bf16 direct-to-LDS, pre-swizzled src
      int c = c0+i, row = c*8 + srow;
      gld_lds16(A + (size_t)row*lda + k0 + ((l7^srow)*8), (char*)As + c*1024);
    }
    #pragma unroll
    for (int i=0;i<4;++i){                          // B fp32 reg-staged, swizzled write
      int c = c0+i, row = c*8 + srow;
      int n = nb*128 + row - noff;
      if constexpr (MODE==2) n = (n > Vv-1) ? (Vv-1) : n;
      const float* bp = Bt + (size_t)n*lda + k0 + l7*8;
      f32x4 f0 = *(const f32x4*)bp, f1 = *(const f32x4*)(bp+4);
      *(bf16x8*)((char*)Bs + row*128 + ((l7^srow)<<4)) = pack8(f0, f1);
    }
    __syncthreads();
    #pragma unroll
    for (int kk=0;kk<2;++kk){
      bf16x8 af[4], bq[4];
      const int ko = kk*64 + (lane>>4)*16;
      const int sw = ko ^ (l7<<4);
      #pragma unroll
      for (int i=0;i<4;++i) af[i] = *(const bf16x8*)((const char*)As + (wr*64+i*16+(lane&15))*128 + sw);
      #pragma unroll
      for (int j=0;j<4;++j) bq[j] = *(const bf16x8*)((const char*)Bs + (wc*64+j*16+(lane&15))*128 + sw);
      #pragma unroll
      for (int i=0;i<4;++i)
        #pragma unroll
        for (int j=0;j<4;++j)
          acc[i][j] = mfma16(af[i], bq[j], acc[i][j]);
    }
    __syncthreads();
  }
  const int lo = lane&15, hi = lane>>4;
  #pragma unroll
  for (int i=0;i<4;++i){
    #pragma unroll
    for (int j=0;j<4;++j){
      int n = nb*128 + wc*64 + j*16 + lo - noff;
      #pragma unroll
      for (int q=0;q<4;++q){
        int m = wr*64 + i*16 + hi*4 + q;
        float v = acc[i][j][q];
        if constexpr (MODE==2){
          if (n < Vv) O0[(size_t)m*Vv + n] = v + bias[n];
        } else {
          atomicAdd(&Ot[(size_t)m*ostride + n], v);
        }
      }
    }
  }
}

// ---------------- softmax over S=512 per batch row ----------------
__global__ void k_softmax(const float* __restrict__ scores, float* __restrict__ attn)
{
  __shared__ float red[512];
  const int b = blockIdx.x, tid = threadIdx.x;
  float v = scores[b*Ss + tid];
  red[tid] = v; __syncthreads();
  for (int off=256; off>0; off>>=1){ if (tid<off) red[tid] = fmaxf(red[tid], red[tid+off]); __syncthreads(); }
  float mx = red[0]; __syncthreads();
  float e = __expf(v - mx);
  red[tid] = e; __syncthreads();
  for (int off=256; off>0; off>>=1){ if (tid<off) red[tid] += red[tid+off]; __syncthreads(); }
  attn[b*Ss + tid] = e / red[0];
}

// ---------------- ctx partial: bf16 enc, 4 row-chunks of 128, vectorized ----------------
__global__ void k_ctx_bf16(const short* __restrict__ encb, const float* __restrict__ attn,
                           float* __restrict__ ctxp)
{
  __shared__ float a[128];
  const int bid = blockIdx.x, b = bid>>2, ch = bid&3, tid = threadIdx.x;  // 256 thr
  if (tid < 128) a[tid] = attn[b*Ss + ch*128 + tid];
  __syncthreads();
  const short* e0 = encb + (size_t)(b*Ss + ch*128)*TWOH + tid*8;
  float s[8] = {};
  for (int r=0; r<128; ++r){
    bf16x8 v = *(const bf16x8*)(e0 + (size_t)r*TWOH);
    float w = a[r];
    #pragma unroll
    for (int j=0;j<8;++j) s[j] += w * bf2f(v[j]);
  }
  float* o = ctxp + (size_t)ch*Bb*TWOH + (size_t)b*TWOH + tid*8;
  #pragma unroll
  for (int j=0;j<8;++j) o[j] = s[j];
}

__global__ void k_ctxfin(const float* __restrict__ ctxp, short* __restrict__ xb)
{
  const int g = blockIdx.x*256 + threadIdx.x;   // b*2048 + col, 1024 blocks
  const int b = g >> 11, col = g & 2047;
  const int N = Bb*TWOH;
  float v = ctxp[g] + ctxp[N+g] + ctxp[2*N+g] + ctxp[3*N+g];
  xb[b*2560 + 512 + col] = f2bf(v);
}

// fallback (small ws): fp32 enc, writes xb directly
__global__ void k_ctx_f32(const float* __restrict__ enc, const float* __restrict__ attn,
                          short* __restrict__ xb)
{
  __shared__ float a[512];
  const int ch = blockIdx.x, b = blockIdx.y, tid = threadIdx.x;
  a[tid]     = attn[b*Ss + tid];
  a[tid+256] = attn[b*Ss + tid + 256];
  __syncthreads();
  const float* e0 = enc + (size_t)b*Ss*TWOH + ch*256 + tid;
  float s0=0.f, s1=0.f, s2=0.f, s3=0.f;
  for (int s=0; s<512; s+=4){
    s0 += a[s]   * e0[(size_t)(s  )*TWOH];
    s1 += a[s+1] * e0[(size_t)(s+1)*TWOH];
    s2 += a[s+2] * e0[(size_t)(s+2)*TWOH];
    s3 += a[s+3] * e0[(size_t)(s+3)*TWOH];
  }
  xb[b*2560 + 512 + ch*256 + tid] = f2bf(s0+s1+s2+s3);
}

// ---------------- GRU gates + h_new ----------------
__global__ void k_gates(const float* __restrict__ gx, const float* __restrict__ gh,
                        const float* __restrict__ b_ih, const float* __restrict__ b_hh,
                        const float* __restrict__ h, float* __restrict__ hnew_out,
                        short* __restrict__ hnewb)
{
  const int gid = blockIdx.x*256 + threadIdx.x;
  const int b = gid >> 10, j = gid & 1023;
  float xr = gx[b*3072 + j]        + b_ih[j];
  float xz = gx[b*3072 + 1024 + j] + b_ih[1024+j];
  float xn = gx[b*3072 + 2048 + j] + b_ih[2048+j];
  float hr = gh[b*3072 + j]        + b_hh[j];
  float hz = gh[b*3072 + 1024 + j] + b_hh[1024+j];
  float hn = gh[b*3072 + 2048 + j] + b_hh[2048+j];
  float r = 1.f/(1.f + __expf(-(xr+hr)));
  float z = 1.f/(1.f + __expf(-(xz+hz)));
  float n = tanhf(xn + r*hn);
  float hv = (1.f - z)*n + z*h[b*Hh + j];
  hnew_out[gid] = hv;
  hnewb[gid] = f2bf(hv);
}

extern "C" void kernel_launch(void* const* d_in, const int* in_sizes, int n_in,
                              void* d_out, int out_size, void* d_ws, size_t ws_size,
                              hipStream_t stream)
{
  const int*   dec   = (const int*)  d_in[0];
  const float* h     = (const float*)d_in[1];
  const float* enc   = (const float*)d_in[2];
  const float* emb   = (const float*)d_in[3];
  const float* W_ah  = (const float*)d_in[4];
  const float* b_ah  = (const float*)d_in[5];
  const float* W_ae  = (const float*)d_in[6];
  const float* b_ae  = (const float*)d_in[7];
  const float* wsc   = (const float*)d_in[8];
  const float* W_ih  = (const float*)d_in[9];
  const float* W_hh  = (const float*)d_in[10];
  const float* b_ih  = (const float*)d_in[11];
  const float* b_hh  = (const float*)d_in[12];
  const float* W_out = (const float*)d_in[13];
  const float* b_out = (const float*)d_in[14];
  float* out = (float*)d_out;
  float* hnew_out = out + (size_t)Bb*Vv;

  char* w = (char*)d_ws;
  float* scores = (float*)w;  w += (size_t)65536*4;    // zeroed (atomic target)
  float* ahb    = (float*)w;  w += (size_t)131072*4;   // zeroed
  float* ghb    = (float*)w;  w += (size_t)393216*4;   // zeroed
  float* gxb    = (float*)w;  w += (size_t)393216*4;   // zeroed
  size_t zero_bytes = (size_t)(w - (char*)d_ws);
  float* attn   = (float*)w;  w += (size_t)65536*4;
  short* waeb   = (short*)w;  w += (size_t)2097152*2;
  short* xb     = (short*)w;  w += (size_t)128*2560*2;
  short* hb     = (short*)w;  w += (size_t)131072*2;
  short* hnb    = (short*)w;  w += (size_t)131072*2;
  float* ctxp   = (float*)w;  w += (size_t)4*Bb*TWOH*4;
  short* encb   = (short*)w;  w += (size_t)65536*2048*2;
  const bool big = ((size_t)(w - (char*)d_ws) <= ws_size);

  hipMemsetAsync(d_ws, 0, zero_bytes, stream);
  k_prep<<<4096, 256, 0, stream>>>(W_ae, waeb, h, hb, dec, emb, xb);
  k_gemm128<0><<<dim3(32,2), 256, 0, stream>>>(hb, 1024, W_ah, W_hh, ahb, ghb, nullptr, 8);
  k_scores<<<4096, 256, 0, stream>>>(enc, waeb, ahb, b_ah, b_ae, wsc, scores,
                                     big ? encb : nullptr);
  k_softmax<<<128, 512, 0, stream>>>(scores, attn);
  if (big){
    k_ctx_bf16<<<512, 256, 0, stream>>>(encb, attn, ctxp);
    k_ctxfin<<<1024, 256, 0, stream>>>(ctxp, xb);
  } else {
    k_ctx_f32<<<dim3(8,128), 256, 0, stream>>>(enc, attn, xb);
  }
  k_gemm128<1><<<dim3(24,4), 256, 0, stream>>>(xb, 2560, W_ih, nullptr, gxb, nullptr, nullptr, 10);
  k_gates<<<512, 256, 0, stream>>>(gxb, ghb, b_ih, b_hh, h, hnew_out, hnb);
  k_gemm128<2><<<dim3(393,1), 256, 0, stream>>>(hnb, 1024, W_out, nullptr, out, nullptr, b_out, 16);
}

// Round 4
// 729.525 us; speedup vs baseline: 1.3939x; 1.3939x over previous
//
#include <hip/hip_runtime.h>
#include <hip/hip_bf16.h>

#define DEVI __device__ __forceinline__

typedef short bf16x8 __attribute__((ext_vector_type(8)));
typedef float f32x4  __attribute__((ext_vector_type(4)));

static constexpr int Bb   = 128;
static constexpr int Ss   = 512;
static constexpr int Hh   = 1024;
static constexpr int Ee   = 512;
static constexpr int Vv   = 50257;
static constexpr int TWOH = 2048;

DEVI short f2bf(float f){ __hip_bfloat16 h = __float2bfloat16(f); return *reinterpret_cast<short*>(&h); }
DEVI float bf2f(short s){ __hip_bfloat16 h = *reinterpret_cast<__hip_bfloat16*>(&s); return __bfloat162float(h); }

DEVI bf16x8 pack8(f32x4 a, f32x4 b){
  bf16x8 v;
  v[0]=f2bf(a[0]); v[1]=f2bf(a[1]); v[2]=f2bf(a[2]); v[3]=f2bf(a[3]);
  v[4]=f2bf(b[0]); v[5]=f2bf(b[1]); v[6]=f2bf(b[2]); v[7]=f2bf(b[3]);
  return v;
}

DEVI void gld_lds16(const void* g, void* l){
  __builtin_amdgcn_global_load_lds((const __attribute__((address_space(1))) void*)g,
                                   (__attribute__((address_space(3))) void*)l, 16, 0, 0);
}

DEVI f32x4 mfma16(bf16x8 a, bf16x8 b, f32x4 c){
  return __builtin_amdgcn_mfma_f32_16x16x32_bf16(a, b, c, 0, 0, 0);
}

// ---------------- enc fp32 -> bf16, fully vectorized streaming pass ----------------
// B*S*2H = 134,217,728 elems; 65536 blocks x 256 thr x 8 elems covers it exactly.
__global__ void k_enc2bf(const float* __restrict__ enc, short* __restrict__ encb)
{
  const size_t i = ((size_t)blockIdx.x*256 + threadIdx.x) * 8;
  f32x4 f0 = *(const f32x4*)(enc + i);
  f32x4 f1 = *(const f32x4*)(enc + i + 4);
  *(bf16x8*)(encb + i) = pack8(f0, f1);
}

// ---------------- prep: convert W_ae->bf16, h->bf16, gather emb into x_bf16 ----------------
__global__ void k_prep(const float* __restrict__ wae, short* __restrict__ waeb,
                       const float* __restrict__ h, short* __restrict__ hb,
                       const int* __restrict__ dec_in, const float* __restrict__ emb,
                       short* __restrict__ xb)
{
  const int total_wae = Hh*TWOH;
  const int total_h   = Bb*Hh;
  const int total_emb = Bb*Ee;
  const int total = total_wae + total_h + total_emb;
  for (int i = blockIdx.x*blockDim.x + threadIdx.x; i < total; i += gridDim.x*blockDim.x){
    if (i < total_wae) waeb[i] = f2bf(wae[i]);
    else if (i < total_wae + total_h){ int j = i - total_wae; hb[j] = f2bf(h[j]); }
    else {
      int j = i - total_wae - total_h;
      int b = j >> 9, e = j & 511;
      xb[b*2560 + e] = f2bf(emb[(size_t)dec_in[b]*Ee + e]);
    }
  }
}

// ---------------- scores GEMM: M=65536 x N=1024 x K=2048, fused tanh-reduce ------
// Linear block mapping (round-1: p%8==nb ties each XCD to ONE L2-resident B tile,
// A streams with max MLP). BF16A: A read from pre-converted encb via global_load_lds
// with pre-swizzled source; fallback reg-stages fp32 enc. T2 XOR swizzle throughout.
template<bool BF16A>
__launch_bounds__(256)
__global__ void k_scores(const float* __restrict__ enc, const short* __restrict__ encbf,
                         const short* __restrict__ waeb,
                         const float* __restrict__ ahb, const float* __restrict__ b_ah,
                         const float* __restrict__ b_ae, const float* __restrict__ wsc,
                         float* __restrict__ scores)
{
  __shared__ __align__(16) short As[128*64];
  __shared__ __align__(16) short Bs[128*64];
  const int p  = blockIdx.x;
  const int rt = p >> 3, nb = p & 7;
  const int tid = threadIdx.x, wid = tid>>6, lane = tid&63;
  const int wr = wid>>1, wc = wid&1;
  const int srow = lane>>3, l7 = lane&7;
  const int c0 = wid*4;
  f32x4 acc[4][4] = {};
  const float* Af  = enc   + (size_t)rt*128*TWOH;
  const short* Ab  = encbf + (size_t)rt*128*TWOH;
  const short* Bbp = waeb  + (size_t)nb*128*TWOH;

  for (int kt = 0; kt < 32; ++kt){
    const int k0 = kt*64;
    #pragma unroll
    for (int i=0;i<4;++i){                          // A stage
      int c = c0+i, row = c*8 + srow;
      if constexpr (BF16A){
        gld_lds16(Ab + (size_t)row*TWOH + k0 + ((l7^srow)*8), (char*)As + c*1024);
      } else {
        const float* bp = Af + (size_t)row*TWOH + k0 + l7*8;
        f32x4 f0 = *(const f32x4*)bp, f1 = *(const f32x4*)(bp+4);
        *(bf16x8*)((char*)As + row*128 + ((l7^srow)<<4)) = pack8(f0, f1);
      }
    }
    #pragma unroll
    for (int i=0;i<4;++i){                          // B: bf16 direct-to-LDS, pre-swizzled src
      int c = c0+i, row = c*8 + srow;
      gld_lds16(Bbp + (size_t)row*TWOH + k0 + ((l7^srow)*8), (char*)Bs + c*1024);
    }
    __syncthreads();
    #pragma unroll
    for (int kk=0;kk<2;++kk){
      bf16x8 af[4], bq[4];
      const int ko = kk*64 + (lane>>4)*16;
      const int sw = ko ^ (l7<<4);
      #pragma unroll
      for (int i=0;i<4;++i) af[i] = *(const bf16x8*)((const char*)As + (wr*64+i*16+(lane&15))*128 + sw);
      #pragma unroll
      for (int j=0;j<4;++j) bq[j] = *(const bf16x8*)((const char*)Bs + (wc*64+j*16+(lane&15))*128 + sw);
      #pragma unroll
      for (int i=0;i<4;++i)
        #pragma unroll
        for (int j=0;j<4;++j)
          acc[i][j] = mfma16(af[i], bq[j], acc[i][j]);
    }
    __syncthreads();
  }
  // epilogue: scores[m] += sum_n tanh(ah[b,n]+b_ah+b_ae+ae)*w_score[n]
  const int lo = lane&15, hi = lane>>4;
  const int b = rt>>2;
  float w4[4], t4[4];
  #pragma unroll
  for (int j=0;j<4;++j){
    int n = nb*128 + wc*64 + j*16 + lo;
    w4[j] = wsc[n];
    t4[j] = ahb[b*Hh + n] + b_ah[n] + b_ae[n];
  }
  #pragma unroll
  for (int i=0;i<4;++i){
    #pragma unroll
    for (int q2=0;q2<4;++q2){
      int m = rt*128 + wr*64 + i*16 + hi*4 + q2;
      float s = 0.f;
      #pragma unroll
      for (int j=0;j<4;++j) s += tanhf(t4[j] + acc[i][j][q2]) * w4[j];
      s += __shfl_xor(s,1); s += __shfl_xor(s,2); s += __shfl_xor(s,4); s += __shfl_xor(s,8);
      if (lo == 0) atomicAdd(&scores[m], s);
    }
  }
}

// ---------------- generic 128-row GEMM: A[128,K] bf16 ws, B[N,K] fp32 global --------------
template<int MODE>
__launch_bounds__(256)
__global__ void k_gemm128(const short* __restrict__ A, int lda,
                          const float* __restrict__ B0, const float* __restrict__ B1,
                          float* __restrict__ O0, float* __restrict__ O1,
                          const float* __restrict__ bias, int kiters)
{
  __shared__ __align__(16) short As[128*64];
  __shared__ __align__(16) short Bs[128*64];
  const int nb = blockIdx.x;
  const int tid = threadIdx.x, wid = tid>>6, lane = tid&63;
  const int wr = wid>>1, wc = wid&1;
  const int srow = lane>>3, l7 = lane&7;
  const int c0 = wid*4;

  const float* Bt; int noff; float* Ot; int ostride;
  if constexpr (MODE==0){
    if (nb < 8){ Bt = B0; noff = 0;    Ot = O0; ostride = Hh;   }
    else       { Bt = B1; noff = 1024; Ot = O1; ostride = 3*Hh; }
  } else if constexpr (MODE==1){ Bt = B0; noff = 0; Ot = O0; ostride = 3*Hh; }
  else { Bt = B0; noff = 0; Ot = O0; ostride = Vv; }

  f32x4 acc[4][4] = {};
  const int kt0 = blockIdx.y * kiters;
  for (int kt = kt0; kt < kt0 + kiters; ++kt){
    const int k0 = kt*64;
    #pragma unroll
    for (int i=0;i<4;++i){                          // A bf16 direct-to-LDS, pre-swizzled src
      int c = c0+i, row = c*8 + srow;
      gld_lds16(A + (size_t)row*lda + k0 + ((l7^srow)*8), (char*)As + c*1024);
    }
    #pragma unroll
    for (int i=0;i<4;++i){                          // B fp32 reg-staged, swizzled write
      int c = c0+i, row = c*8 + srow;
      int n = nb*128 + row - noff;
      if constexpr (MODE==2) n = (n > Vv-1) ? (Vv-1) : n;
      const float* bp = Bt + (size_t)n*lda + k0 + l7*8;
      f32x4 f0 = *(const f32x4*)bp, f1 = *(const f32x4*)(bp+4);
      *(bf16x8*)((char*)Bs + row*128 + ((l7^srow)<<4)) = pack8(f0, f1);
    }
    __syncthreads();
    #pragma unroll
    for (int kk=0;kk<2;++kk){
      bf16x8 af[4], bq[4];
      const int ko = kk*64 + (lane>>4)*16;
      const int sw = ko ^ (l7<<4);
      #pragma unroll
      for (int i=0;i<4;++i) af[i] = *(const bf16x8*)((const char*)As + (wr*64+i*16+(lane&15))*128 + sw);
      #pragma unroll
      for (int j=0;j<4;++j) bq[j] = *(const bf16x8*)((const char*)Bs + (wc*64+j*16+(lane&15))*128 + sw);
      #pragma unroll
      for (int i=0;i<4;++i)
        #pragma unroll
        for (int j=0;j<4;++j)
          acc[i][j] = mfma16(af[i], bq[j], acc[i][j]);
    }
    __syncthreads();
  }
  const int lo = lane&15, hi = lane>>4;
  #pragma unroll
  for (int i=0;i<4;++i){
    #pragma unroll
    for (int j=0;j<4;++j){
      int n = nb*128 + wc*64 + j*16 + lo - noff;
      #pragma unroll
      for (int q=0;q<4;++q){
        int m = wr*64 + i*16 + hi*4 + q;
        float v = acc[i][j][q];
        if constexpr (MODE==2){
          if (n < Vv) O0[(size_t)m*Vv + n] = v + bias[n];
        } else {
          atomicAdd(&Ot[(size_t)m*ostride + n], v);
        }
      }
    }
  }
}

// ---------------- softmax over S=512 per batch row ----------------
__global__ void k_softmax(const float* __restrict__ scores, float* __restrict__ attn)
{
  __shared__ float red[512];
  const int b = blockIdx.x, tid = threadIdx.x;
  float v = scores[b*Ss + tid];
  red[tid] = v; __syncthreads();
  for (int off=256; off>0; off>>=1){ if (tid<off) red[tid] = fmaxf(red[tid], red[tid+off]); __syncthreads(); }
  float mx = red[0]; __syncthreads();
  float e = __expf(v - mx);
  red[tid] = e; __syncthreads();
  for (int off=256; off>0; off>>=1){ if (tid<off) red[tid] += red[tid+off]; __syncthreads(); }
  attn[b*Ss + tid] = e / red[0];
}

// ---------------- ctx partial: bf16 enc, 4 row-chunks of 128, vectorized ----------------
__global__ void k_ctx_bf16(const short* __restrict__ encb, const float* __restrict__ attn,
                           float* __restrict__ ctxp)
{
  __shared__ float a[128];
  const int bid = blockIdx.x, b = bid>>2, ch = bid&3, tid = threadIdx.x;
  if (tid < 128) a[tid] = attn[b*Ss + ch*128 + tid];
  __syncthreads();
  const short* e0 = encb + (size_t)(b*Ss + ch*128)*TWOH + tid*8;
  float s[8] = {};
  for (int r=0; r<128; ++r){
    bf16x8 v = *(const bf16x8*)(e0 + (size_t)r*TWOH);
    float w = a[r];
    #pragma unroll
    for (int j=0;j<8;++j) s[j] += w * bf2f(v[j]);
  }
  float* o = ctxp + (size_t)ch*Bb*TWOH + (size_t)b*TWOH + tid*8;
  #pragma unroll
  for (int j=0;j<8;++j) o[j] = s[j];
}

__global__ void k_ctxfin(const float* __restrict__ ctxp, short* __restrict__ xb)
{
  const int g = blockIdx.x*256 + threadIdx.x;
  const int b = g >> 11, col = g & 2047;
  const int N = Bb*TWOH;
  float v = ctxp[g] + ctxp[N+g] + ctxp[2*N+g] + ctxp[3*N+g];
  xb[b*2560 + 512 + col] = f2bf(v);
}

// fallback (small ws): fp32 enc, writes xb directly
__global__ void k_ctx_f32(const float* __restrict__ enc, const float* __restrict__ attn,
                          short* __restrict__ xb)
{
  __shared__ float a[512];
  const int ch = blockIdx.x, b = blockIdx.y, tid = threadIdx.x;
  a[tid]     = attn[b*Ss + tid];
  a[tid+256] = attn[b*Ss + tid + 256];
  __syncthreads();
  const float* e0 = enc + (size_t)b*Ss*TWOH + ch*256 + tid;
  float s0=0.f, s1=0.f, s2=0.f, s3=0.f;
  for (int s=0; s<512; s+=4){
    s0 += a[s]   * e0[(size_t)(s  )*TWOH];
    s1 += a[s+1] * e0[(size_t)(s+1)*TWOH];
    s2 += a[s+2] * e0[(size_t)(s+2)*TWOH];
    s3 += a[s+3] * e0[(size_t)(s+3)*TWOH];
  }
  xb[b*2560 + 512 + ch*256 + tid] = f2bf(s0+s1+s2+s3);
}

// ---------------- GRU gates + h_new ----------------
__global__ void k_gates(const float* __restrict__ gx, const float* __restrict__ gh,
                        const float* __restrict__ b_ih, const float* __restrict__ b_hh,
                        const float* __restrict__ h, float* __restrict__ hnew_out,
                        short* __restrict__ hnewb)
{
  const int gid = blockIdx.x*256 + threadIdx.x;
  const int b = gid >> 10, j = gid & 1023;
  float xr = gx[b*3072 + j]        + b_ih[j];
  float xz = gx[b*3072 + 1024 + j] + b_ih[1024+j];
  float xn = gx[b*3072 + 2048 + j] + b_ih[2048+j];
  float hr = gh[b*3072 + j]        + b_hh[j];
  float hz = gh[b*3072 + 1024 + j] + b_hh[1024+j];
  float hn = gh[b*3072 + 2048 + j] + b_hh[2048+j];
  float r = 1.f/(1.f + __expf(-(xr+hr)));
  float z = 1.f/(1.f + __expf(-(xz+hz)));
  float n = tanhf(xn + r*hn);
  float hv = (1.f - z)*n + z*h[b*Hh + j];
  hnew_out[gid] = hv;
  hnewb[gid] = f2bf(hv);
}

extern "C" void kernel_launch(void* const* d_in, const int* in_sizes, int n_in,
                              void* d_out, int out_size, void* d_ws, size_t ws_size,
                              hipStream_t stream)
{
  const int*   dec   = (const int*)  d_in[0];
  const float* h     = (const float*)d_in[1];
  const float* enc   = (const float*)d_in[2];
  const float* emb   = (const float*)d_in[3];
  const float* W_ah  = (const float*)d_in[4];
  const float* b_ah  = (const float*)d_in[5];
  const float* W_ae  = (const float*)d_in[6];
  const float* b_ae  = (const float*)d_in[7];
  const float* wsc   = (const float*)d_in[8];
  const float* W_ih  = (const float*)d_in[9];
  const float* W_hh  = (const float*)d_in[10];
  const float* b_ih  = (const float*)d_in[11];
  const float* b_hh  = (const float*)d_in[12];
  const float* W_out = (const float*)d_in[13];
  const float* b_out = (const float*)d_in[14];
  float* out = (float*)d_out;
  float* hnew_out = out + (size_t)Bb*Vv;

  char* w = (char*)d_ws;
  float* scores = (float*)w;  w += (size_t)65536*4;    // zeroed (atomic target)
  float* ahb    = (float*)w;  w += (size_t)131072*4;   // zeroed
  float* ghb    = (float*)w;  w += (size_t)393216*4;   // zeroed
  float* gxb    = (float*)w;  w += (size_t)393216*4;   // zeroed
  size_t zero_bytes = (size_t)(w - (char*)d_ws);
  float* attn   = (float*)w;  w += (size_t)65536*4;
  short* waeb   = (short*)w;  w += (size_t)2097152*2;
  short* xb     = (short*)w;  w += (size_t)128*2560*2;
  short* hb     = (short*)w;  w += (size_t)131072*2;
  short* hnb    = (short*)w;  w += (size_t)131072*2;
  float* ctxp   = (float*)w;  w += (size_t)4*Bb*TWOH*4;
  short* encb   = (short*)w;  w += (size_t)65536*2048*2;
  const bool big = ((size_t)(w - (char*)d_ws) <= ws_size);

  hipMemsetAsync(d_ws, 0, zero_bytes, stream);
  if (big) k_enc2bf<<<65536, 256, 0, stream>>>(enc, encb);   // 134,217,728 elems / (256*8)
  k_prep<<<4096, 256, 0, stream>>>(W_ae, waeb, h, hb, dec, emb, xb);
  k_gemm128<0><<<dim3(32,2), 256, 0, stream>>>(hb, 1024, W_ah, W_hh, ahb, ghb, nullptr, 8);
  if (big)
    k_scores<true><<<4096, 256, 0, stream>>>(enc, encb, waeb, ahb, b_ah, b_ae, wsc, scores);
  else
    k_scores<false><<<4096, 256, 0, stream>>>(enc, nullptr, waeb, ahb, b_ah, b_ae, wsc, scores);
  k_softmax<<<128, 512, 0, stream>>>(scores, attn);
  if (big){
    k_ctx_bf16<<<512, 256, 0, stream>>>(encb, attn, ctxp);
    k_ctxfin<<<1024, 256, 0, stream>>>(ctxp, xb);
  } else {
    k_ctx_f32<<<dim3(8,128), 256, 0, stream>>>(enc, attn, xb);
  }
  k_gemm128<1><<<dim3(24,4), 256, 0, stream>>>(xb, 2560, W_ih, nullptr, gxb, nullptr, nullptr, 10);
  k_gates<<<512, 256, 0, stream>>>(gxb, ghb, b_ih, b_hh, h, hnew_out, hnb);
  k_gemm128<2><<<dim3(393,1), 256, 0, stream>>>(hnb, 1024, W_out, nullptr, out, nullptr, b_out, 16);
}